// Round 1
// baseline (12268.393 us; speedup 1.0000x reference)
//
#include <hip/hip_runtime.h>

#define DIMC 384
#define NTOK 1024
#define BATCH 32

// ---------------------------------------------------------------------------
// proj_kernel: Out[b][n][d] = sum_c X[b][c][n] * W[d][c] + bias[d]
// One kernel computes q (from rgb), k, v (from ms), selected by blockIdx.z%3.
// Block tile 64n x 64d, 256 threads, 4x4 per thread, c-chunks of 32.
// grid (NTOK/64, DIMC/64, BATCH*3)
// ---------------------------------------------------------------------------
__global__ __launch_bounds__(256) void proj_kernel(
    const float* __restrict__ rgb, const float* __restrict__ ms,
    const float* __restrict__ Wq, const float* __restrict__ bq,
    const float* __restrict__ Wk, const float* __restrict__ bk,
    const float* __restrict__ Wv, const float* __restrict__ bv,
    float* __restrict__ qws, float* __restrict__ kws, float* __restrict__ vws)
{
    __shared__ float xs[32][65];   // [c][n] tile, +1 pad
    __shared__ float wsm[64][33];  // [d][c] tile, +1 pad

    const int t  = threadIdx.x;
    const int s  = blockIdx.z % 3;
    const int b  = blockIdx.z / 3;
    const int n0 = blockIdx.x * 64;
    const int d0 = blockIdx.y * 64;

    const float* X    = (s == 0) ? rgb : ms;
    const float* W    = (s == 0) ? Wq : (s == 1) ? Wk : Wv;
    const float* bias = (s == 0) ? bq : (s == 1) ? bk : bv;
    float* Out        = (s == 0) ? qws : (s == 1) ? kws : vws;

    const int tx = t & 15;   // d sub-group
    const int ty = t >> 4;   // n sub-group

    float acc[4][4];
#pragma unroll
    for (int i = 0; i < 4; ++i)
#pragma unroll
        for (int j = 0; j < 4; ++j) acc[i][j] = 0.f;

    for (int c0 = 0; c0 < DIMC; c0 += 32) {
        __syncthreads();
#pragma unroll
        for (int e = 0; e < 8; ++e) {
            int lin = e * 256 + t;
            int cc = lin >> 6, nn = lin & 63;
            xs[cc][nn] = X[((size_t)b * DIMC + (c0 + cc)) * NTOK + n0 + nn];
        }
#pragma unroll
        for (int e = 0; e < 8; ++e) {
            int lin = e * 256 + t;
            int dd = lin >> 5, cc = lin & 31;
            wsm[dd][cc] = W[(size_t)(d0 + dd) * DIMC + c0 + cc];
        }
        __syncthreads();
#pragma unroll
        for (int cc = 0; cc < 32; ++cc) {
            float xr[4], wr[4];
#pragma unroll
            for (int i = 0; i < 4; ++i) xr[i] = xs[cc][ty + 16 * i];
#pragma unroll
            for (int j = 0; j < 4; ++j) wr[j] = wsm[tx + 16 * j][cc];
#pragma unroll
            for (int i = 0; i < 4; ++i)
#pragma unroll
                for (int j = 0; j < 4; ++j) acc[i][j] += xr[i] * wr[j];
        }
    }

#pragma unroll
    for (int i = 0; i < 4; ++i) {
        int nn = ty + 16 * i;
#pragma unroll
        for (int j = 0; j < 4; ++j) {
            int dd = tx + 16 * j;
            Out[((size_t)b * NTOK + n0 + nn) * DIMC + d0 + dd] = acc[i][j] + bias[d0 + dd];
        }
    }
}

// ---------------------------------------------------------------------------
// attn_kernel: flash-style attention + fused final projection.
// Block handles (batch b, 32 queries). q tile resident in LDS; streams
// 32-wide k/v tiles in 64-wide d/c chunks; online softmax; O accum in regs
// (2n x 24c per thread); epilogue computes Wf @ O + bf directly to d_out.
// grid (NTOK/32, BATCH), 256 threads. LDS = 62208 B -> 2 blocks/CU.
// ---------------------------------------------------------------------------
__global__ __launch_bounds__(256) void attn_kernel(
    const float* __restrict__ qws, const float* __restrict__ kws,
    const float* __restrict__ vws,
    const float* __restrict__ Wf, const float* __restrict__ bf_,
    float* __restrict__ out)
{
    __shared__ float qs[32][385];            // q tile, later reused for normalized O
    __shared__ float kv[32][65];             // k / v / Wf chunk
    __shared__ float sp[32][33];             // scores -> probabilities
    __shared__ float row_m[32], row_l[32], row_a[32];

    const int t  = threadIdx.x;
    const int b  = blockIdx.y;
    const int n0 = blockIdx.x * 32;

    const float* qb = qws + ((size_t)b * NTOK + n0) * DIMC;
    const float* kb = kws + (size_t)b * NTOK * DIMC;
    const float* vb = vws + (size_t)b * NTOK * DIMC;

    // load q tile (32 x 384), fully coalesced
#pragma unroll
    for (int e = 0; e < 48; ++e) {
        int lin = e * 256 + t;
        int r = lin / DIMC, c = lin - r * DIMC;
        qs[r][c] = qb[(size_t)r * DIMC + c];
    }
    if (t < 32) { row_m[t] = -1e30f; row_l[t] = 0.f; }

    const int ip = t >> 4, jp = t & 15;   // scores: rows {2ip,2ip+1} x cols {2jp,2jp+1}
    const int np = t >> 4, cq = t & 15;   // O: rows {2np,2np+1} x cols cq+16k

    float acc2[2][24];
#pragma unroll
    for (int i = 0; i < 2; ++i)
#pragma unroll
        for (int k = 0; k < 24; ++k) acc2[i][k] = 0.f;

    const float scale = 0.05103103630798288f;  // 1/sqrt(384)

    for (int m0 = 0; m0 < NTOK; m0 += 32) {
        // ---- scores S[32n x 32m] ----
        float sacc[2][2] = {{0.f, 0.f}, {0.f, 0.f}};
        for (int dc = 0; dc < DIMC; dc += 64) {
            __syncthreads();   // previous kv readers done
#pragma unroll
            for (int e = 0; e < 8; ++e) {
                int lin = e * 256 + t; int j = lin >> 6, d = lin & 63;
                kv[j][d] = kb[(size_t)(m0 + j) * DIMC + dc + d];
            }
            __syncthreads();
#pragma unroll
            for (int d = 0; d < 64; ++d) {
                float q0 = qs[2 * ip][dc + d], q1 = qs[2 * ip + 1][dc + d];
                float k0 = kv[2 * jp][d],      k1 = kv[2 * jp + 1][d];
                sacc[0][0] += q0 * k0; sacc[0][1] += q0 * k1;
                sacc[1][0] += q1 * k0; sacc[1][1] += q1 * k1;
            }
        }
        sp[2 * ip][2 * jp]         = sacc[0][0] * scale;
        sp[2 * ip][2 * jp + 1]     = sacc[0][1] * scale;
        sp[2 * ip + 1][2 * jp]     = sacc[1][0] * scale;
        sp[2 * ip + 1][2 * jp + 1] = sacc[1][1] * scale;
        __syncthreads();

        // ---- online softmax (one thread per row) ----
        if (t < 32) {
            float mold = row_m[t];
            float mx = mold;
#pragma unroll
            for (int j = 0; j < 32; ++j) mx = fmaxf(mx, sp[t][j]);
            float a = __expf(mold - mx);
            float ssum = 0.f;
#pragma unroll
            for (int j = 0; j < 32; ++j) {
                float p = __expf(sp[t][j] - mx);
                sp[t][j] = p;
                ssum += p;
            }
            row_l[t] = row_l[t] * a + ssum;
            row_m[t] = mx;
            row_a[t] = a;
        }
        __syncthreads();

        // ---- O update: rescale + P.V ----
        float a0 = row_a[2 * np], a1 = row_a[2 * np + 1];
#pragma unroll
        for (int k = 0; k < 24; ++k) { acc2[0][k] *= a0; acc2[1][k] *= a1; }

        for (int ci = 0; ci < 6; ++ci) {
            __syncthreads();
#pragma unroll
            for (int e = 0; e < 8; ++e) {
                int lin = e * 256 + t; int j = lin >> 6, c = lin & 63;
                kv[j][c] = vb[(size_t)(m0 + j) * DIMC + ci * 64 + c];
            }
            __syncthreads();
#pragma unroll
            for (int j = 0; j < 32; ++j) {
                float p0 = sp[2 * np][j], p1 = sp[2 * np + 1][j];
#pragma unroll
                for (int k2 = 0; k2 < 4; ++k2) {
                    float vv = kv[j][cq + 16 * k2];
                    acc2[0][4 * ci + k2] += p0 * vv;
                    acc2[1][4 * ci + k2] += p1 * vv;
                }
            }
        }
    }

    // ---- normalize O, park in qs (q no longer needed) ----
    __syncthreads();
    float l0 = 1.f / row_l[2 * np], l1 = 1.f / row_l[2 * np + 1];
#pragma unroll
    for (int k = 0; k < 24; ++k) {
        qs[2 * np][cq + 16 * k]     = acc2[0][k] * l0;
        qs[2 * np + 1][cq + 16 * k] = acc2[1][k] * l1;
    }
    __syncthreads();

    // ---- fused final projection: out[b][dd][n] = Wf @ O + bf ----
    const int nn = t & 31, g = t >> 5;
    for (int gi = 0; gi < 12; ++gi) {
        int dd0 = gi * 32;
        float facc[4] = {0.f, 0.f, 0.f, 0.f};
        for (int ci = 0; ci < 6; ++ci) {
            __syncthreads();
#pragma unroll
            for (int e = 0; e < 8; ++e) {
                int lin = e * 256 + t; int j = lin >> 6, c = lin & 63;
                kv[j][c] = Wf[(size_t)(dd0 + j) * DIMC + ci * 64 + c];
            }
            __syncthreads();
#pragma unroll
            for (int rr = 0; rr < 4; ++rr) {
                int dl = g + 8 * rr;
                float a = 0.f;
#pragma unroll
                for (int c = 0; c < 64; ++c) a += kv[dl][c] * qs[nn][ci * 64 + c];
                facc[rr] += a;
            }
        }
#pragma unroll
        for (int rr = 0; rr < 4; ++rr) {
            int dd = dd0 + g + 8 * rr;
            out[((size_t)b * DIMC + dd) * NTOK + n0 + nn] = facc[rr] + bf_[dd];
        }
    }
}

extern "C" void kernel_launch(void* const* d_in, const int* in_sizes, int n_in,
                              void* d_out, int out_size, void* d_ws, size_t ws_size,
                              hipStream_t stream) {
    const float* rgb = (const float*)d_in[0];
    const float* ms  = (const float*)d_in[1];
    const float* Wq  = (const float*)d_in[2];
    const float* bq  = (const float*)d_in[3];
    const float* Wk  = (const float*)d_in[4];
    const float* bk  = (const float*)d_in[5];
    const float* Wv  = (const float*)d_in[6];
    const float* bv  = (const float*)d_in[7];
    const float* Wf  = (const float*)d_in[8];
    const float* bf_ = (const float*)d_in[9];
    float* outp = (float*)d_out;

    const size_t BND = (size_t)BATCH * NTOK * DIMC;  // 12.58M floats each
    float* qws = (float*)d_ws;
    float* kws = qws + BND;
    float* vws = kws + BND;
    // ws use: 3 * 50.33 MB = 151 MB

    proj_kernel<<<dim3(NTOK / 64, DIMC / 64, BATCH * 3), 256, 0, stream>>>(
        rgb, ms, Wq, bq, Wk, bk, Wv, bv, qws, kws, vws);
    attn_kernel<<<dim3(NTOK / 32, BATCH), 256, 0, stream>>>(
        qws, kws, vws, Wf, bf_, outp);
}

// Round 2
// 879.929 us; speedup vs baseline: 13.9425x; 13.9425x over previous
//
#include <hip/hip_runtime.h>

#define DIMC 384
#define NTOK 1024
#define BATCH 32

using short8 = __attribute__((ext_vector_type(8))) short;
using f32x4  = __attribute__((ext_vector_type(4))) float;
using uint4_ = __attribute__((ext_vector_type(4))) unsigned int;
typedef unsigned short u16;

#define MFMA16 __builtin_amdgcn_mfma_f32_16x16x32_bf16

__device__ __forceinline__ u16 f2bf(float f) {
    unsigned int u = __builtin_bit_cast(unsigned int, f);
    u += 0x7FFFu + ((u >> 16) & 1u);
    return (u16)(u >> 16);
}
__device__ __forceinline__ float bf2f(u16 h) {
    unsigned int u = ((unsigned int)h) << 16;
    return __builtin_bit_cast(float, u);
}

// ---------------------------------------------------------------------------
// transpose_cvt: X (b, c, n) fp32 -> Xt (b, n, c) bf16.  64x64 tiles.
// grid (NTOK/64, DIMC/64, BATCH), 256 threads.
// ---------------------------------------------------------------------------
__global__ __launch_bounds__(256) void transpose_cvt(
    const float* __restrict__ X, u16* __restrict__ Xt)
{
    __shared__ float tl[64 * 65];
    const int b  = blockIdx.z;
    const int n0 = blockIdx.x * 64;
    const int c0 = blockIdx.y * 64;
    const int t  = threadIdx.x;

#pragma unroll
    for (int p = 0; p < 4; ++p) {
        int idx = p * 256 + t;
        int c = idx >> 4, n4 = (idx & 15) * 4;
        f32x4 v = *(const f32x4*)(X + ((size_t)b * DIMC + c0 + c) * NTOK + n0 + n4);
#pragma unroll
        for (int i = 0; i < 4; ++i) tl[c * 65 + n4 + i] = v[i];
    }
    __syncthreads();
#pragma unroll
    for (int p = 0; p < 2; ++p) {
        int idx = p * 256 + t;
        int n = idx >> 3, c8 = (idx & 7) * 8;
        uint4_ pk;
#pragma unroll
        for (int i = 0; i < 4; ++i) {
            u16 lo = f2bf(tl[(c8 + 2 * i) * 65 + n]);
            u16 hi = f2bf(tl[(c8 + 2 * i + 1) * 65 + n]);
            pk[i] = (unsigned int)lo | ((unsigned int)hi << 16);
        }
        *(uint4_*)(Xt + ((size_t)b * NTOK + n0 + n) * DIMC + c0 + c8) = pk;
    }
}

// ---------------------------------------------------------------------------
// wcvt: convert 4 weight matrices (384x384 fp32) to bf16, concatenated.
// grid (72, 4), 256 threads, 8 elems/thread.
// ---------------------------------------------------------------------------
__global__ __launch_bounds__(256) void wcvt(
    const float* __restrict__ w0, const float* __restrict__ w1,
    const float* __restrict__ w2, const float* __restrict__ w3,
    u16* __restrict__ dst)
{
    const float* srcs[4] = {w0, w1, w2, w3};
    const float* s = srcs[blockIdx.y];
    u16* d = dst + (size_t)blockIdx.y * DIMC * DIMC;
    int e0 = (blockIdx.x * 256 + threadIdx.x) * 8;
    f32x4 a = *(const f32x4*)(s + e0);
    f32x4 b = *(const f32x4*)(s + e0 + 4);
    uint4_ pk;
    pk[0] = (unsigned int)f2bf(a[0]) | ((unsigned int)f2bf(a[1]) << 16);
    pk[1] = (unsigned int)f2bf(a[2]) | ((unsigned int)f2bf(a[3]) << 16);
    pk[2] = (unsigned int)f2bf(b[0]) | ((unsigned int)f2bf(b[1]) << 16);
    pk[3] = (unsigned int)f2bf(b[2]) | ((unsigned int)f2bf(b[3]) << 16);
    *(uint4_*)(d + e0) = pk;
}

// ---------------------------------------------------------------------------
// proj_mfma: D[row][col] = sum_c A[row][c] * B[col][c]  (+bias), bf16 out.
// A, B row-major with inner dim DIMC (contiguous c). Output row-major [row][col]
// (ldO = cols). 64x64 tile/block, 4 waves x (16 rows x 64 cols).
//   q: A=rgb_t(b,n,c) B=Wq   -> q_t (b,n,d)   bias over col
//   k: A=ms_t         B=Wk   -> k_t (b,m,d)   bias over col
//   v: A=Wv           B=ms_t -> v_cf (b,d,m)  bias over row
// ---------------------------------------------------------------------------
__global__ __launch_bounds__(256) void proj_mfma(
    const u16* __restrict__ Amat, long aStride,
    const u16* __restrict__ Bmat, long bStride,
    u16* __restrict__ Omat, long oStride, int ldO,
    const float* __restrict__ bias, int biasOnRow)
{
    __shared__ u16 tile[64 * 72];
    const int bz = blockIdx.z;
    const int r0 = blockIdx.y * 64, c0 = blockIdx.x * 64;
    const int t = threadIdx.x, w = t >> 6, lane = t & 63;
    const int l15 = lane & 15, quad = lane >> 4;

    const u16* Ab = Amat + (size_t)bz * aStride;
    const u16* Bb = Bmat + (size_t)bz * bStride;
    u16* Ob = Omat + (size_t)bz * oStride;

    f32x4 acc[4];
#pragma unroll
    for (int i = 0; i < 4; ++i) acc[i] = (f32x4){0.f, 0.f, 0.f, 0.f};

    const u16* aPtr = Ab + (size_t)(r0 + w * 16 + l15) * DIMC + quad * 8;
    const u16* bPtr = Bb + (size_t)(c0 + l15) * DIMC + quad * 8;
#pragma unroll
    for (int dk = 0; dk < 12; ++dk) {
        short8 af = *(const short8*)(aPtr + dk * 32);
#pragma unroll
        for (int mc = 0; mc < 4; ++mc) {
            short8 bfr = *(const short8*)(bPtr + (size_t)mc * 16 * DIMC + dk * 32);
            acc[mc] = MFMA16(af, bfr, acc[mc], 0, 0, 0);
        }
    }

    if (biasOnRow) {
        f32x4 bv = *(const f32x4*)(bias + r0 + w * 16 + quad * 4);
#pragma unroll
        for (int mc = 0; mc < 4; ++mc)
#pragma unroll
            for (int r = 0; r < 4; ++r) acc[mc][r] += bv[r];
    } else {
#pragma unroll
        for (int mc = 0; mc < 4; ++mc) {
            float bc = bias[c0 + mc * 16 + l15];
#pragma unroll
            for (int r = 0; r < 4; ++r) acc[mc][r] += bc;
        }
    }

#pragma unroll
    for (int mc = 0; mc < 4; ++mc)
#pragma unroll
        for (int r = 0; r < 4; ++r)
            tile[(w * 16 + quad * 4 + r) * 72 + mc * 16 + l15] = f2bf(acc[mc][r]);
    __syncthreads();

#pragma unroll
    for (int p = 0; p < 2; ++p) {
        int idx = p * 256 + t;
        int row = idx >> 3, c8 = (idx & 7) * 8;
        uint4_ v = *(const uint4_*)(tile + row * 72 + c8);
        *(uint4_*)(Ob + (size_t)(r0 + row) * ldO + c0 + c8) = v;
    }
}

// ---------------------------------------------------------------------------
// attn_mfma: flash attention (64 queries/block, 4 waves x 16 queries) +
// fused Wf projection. MFMA everywhere; online softmax in registers.
// grid (NTOK/64, BATCH), 256 threads.
// ---------------------------------------------------------------------------
__global__ __launch_bounds__(256, 2) void attn_mfma(
    const u16* __restrict__ qt, const u16* __restrict__ kt,
    const u16* __restrict__ vcf, const u16* __restrict__ Wf_bf,
    const float* __restrict__ bfp, float* __restrict__ out)
{
    __shared__ u16 p_lds[4][16 * 72];   // per-wave P tile (16 q x 64 keys)
    __shared__ u16 o_lds[64 * 392];     // normalized O (64 q x 384 c)

    const int b  = blockIdx.y;
    const int n0 = blockIdx.x * 64;
    const int t = threadIdx.x, w = t >> 6, lane = t & 63;
    const int l15 = lane & 15, quad = lane >> 4;
    const int nw = n0 + w * 16;

    // Q fragments resident in registers (A-layout: row=l15, k=quad*8+j)
    short8 qf[12];
    const u16* qp = qt + ((size_t)b * NTOK + nw + l15) * DIMC + quad * 8;
#pragma unroll
    for (int dk = 0; dk < 12; ++dk) qf[dk] = *(const short8*)(qp + dk * 32);

    f32x4 Oa[24];
#pragma unroll
    for (int i = 0; i < 24; ++i) Oa[i] = (f32x4){0.f, 0.f, 0.f, 0.f};
    float m_run[4], l_run[4];
#pragma unroll
    for (int r = 0; r < 4; ++r) { m_run[r] = -1e30f; l_run[r] = 0.f; }

    const float sc2 = 0.05103103630798288f * 1.4426950408889634f;  // scale*log2(e)

    const u16* kbase = kt  + (size_t)b * NTOK * DIMC;
    const u16* vbase = vcf + (size_t)b * DIMC * NTOK;

    for (int m0 = 0; m0 < NTOK; m0 += 64) {
        // ---- scores S[16 q][64 keys] ----
        f32x4 s[4];
#pragma unroll
        for (int i = 0; i < 4; ++i) s[i] = (f32x4){0.f, 0.f, 0.f, 0.f};
        const u16* kp = kbase + (size_t)(m0 + l15) * DIMC + quad * 8;
#pragma unroll
        for (int dk = 0; dk < 12; ++dk) {
#pragma unroll
            for (int mc = 0; mc < 4; ++mc) {
                short8 kf = *(const short8*)(kp + (size_t)mc * 16 * DIMC + dk * 32);
                s[mc] = MFMA16(qf[dk], kf, s[mc], 0, 0, 0);
            }
        }
#pragma unroll
        for (int mc = 0; mc < 4; ++mc)
#pragma unroll
            for (int r = 0; r < 4; ++r) s[mc][r] *= sc2;

        // ---- online softmax (rows = quad*4+r; reduce over 16 lanes/quad) ----
        float mnew[4], alpha[4];
#pragma unroll
        for (int r = 0; r < 4; ++r) {
            float mx = fmaxf(fmaxf(s[0][r], s[1][r]), fmaxf(s[2][r], s[3][r]));
            mx = fmaxf(mx, __shfl_xor(mx, 1));
            mx = fmaxf(mx, __shfl_xor(mx, 2));
            mx = fmaxf(mx, __shfl_xor(mx, 4));
            mx = fmaxf(mx, __shfl_xor(mx, 8));
            mnew[r] = fmaxf(m_run[r], mx);
            alpha[r] = exp2f(m_run[r] - mnew[r]);
            m_run[r] = mnew[r];
        }
        u16* pw = p_lds[w];
#pragma unroll
        for (int r = 0; r < 4; ++r) {
            float ls = 0.f;
#pragma unroll
            for (int mc = 0; mc < 4; ++mc) {
                float p = exp2f(s[mc][r] - mnew[r]);
                u16 pb = f2bf(p);
                pw[(quad * 4 + r) * 72 + mc * 16 + l15] = pb;
                ls += bf2f(pb);   // denominator from rounded P -> exact normalization
            }
            ls += __shfl_xor(ls, 1);
            ls += __shfl_xor(ls, 2);
            ls += __shfl_xor(ls, 4);
            ls += __shfl_xor(ls, 8);
            l_run[r] = l_run[r] * alpha[r] + ls;
        }
#pragma unroll
        for (int ci = 0; ci < 24; ++ci)
#pragma unroll
            for (int r = 0; r < 4; ++r) Oa[ci][r] *= alpha[r];

        __syncthreads();  // P writes visible; keeps waves lockstep for L1 reuse

        // ---- PV: O[16 q][384 c] += P[16 q][64 m] * V[64 m][384 c] ----
        short8 pa0 = *(const short8*)(pw + l15 * 72 + quad * 8);
        short8 pa1 = *(const short8*)(pw + l15 * 72 + 32 + quad * 8);
        const u16* vp = vbase + (size_t)l15 * NTOK + m0 + quad * 8;
#pragma unroll
        for (int ci = 0; ci < 24; ++ci) {
            short8 v0 = *(const short8*)(vp + (size_t)ci * 16 * NTOK);
            short8 v1 = *(const short8*)(vp + (size_t)ci * 16 * NTOK + 32);
            Oa[ci] = MFMA16(pa0, v0, Oa[ci], 0, 0, 0);
            Oa[ci] = MFMA16(pa1, v1, Oa[ci], 0, 0, 0);
        }
    }

    // ---- normalize O -> bf16 -> LDS ----
    float rl[4];
#pragma unroll
    for (int r = 0; r < 4; ++r) rl[r] = 1.f / l_run[r];
#pragma unroll
    for (int ci = 0; ci < 24; ++ci)
#pragma unroll
        for (int r = 0; r < 4; ++r)
            o_lds[(w * 16 + quad * 4 + r) * 392 + ci * 16 + l15] = f2bf(Oa[ci][r] * rl[r]);
    __syncthreads();

    // ---- fused Wf: F[n][dd] = sum_c O[n][c] * Wf[dd][c] ----
    f32x4 F[24];
#pragma unroll
    for (int i = 0; i < 24; ++i) F[i] = (f32x4){0.f, 0.f, 0.f, 0.f};
#pragma unroll
    for (int ck = 0; ck < 12; ++ck) {
        short8 oa = *(const short8*)(o_lds + (size_t)(w * 16 + l15) * 392 + ck * 32 + quad * 8);
        const u16* wp = Wf_bf + (size_t)l15 * DIMC + ck * 32 + quad * 8;
#pragma unroll
        for (int dj = 0; dj < 24; ++dj) {
            short8 wf = *(const short8*)(wp + (size_t)dj * 16 * DIMC);
            F[dj] = MFMA16(oa, wf, F[dj], 0, 0, 0);
        }
    }
    // store: D rows (quad*4+reg) are consecutive n -> dwordx4 along n
#pragma unroll
    for (int dj = 0; dj < 24; ++dj) {
        int dd = dj * 16 + l15;
        float bb = bfp[dd];
        f32x4 rv = F[dj];
#pragma unroll
        for (int i = 0; i < 4; ++i) rv[i] += bb;
        *(f32x4*)(out + ((size_t)b * DIMC + dd) * NTOK + n0 + w * 16 + quad * 4) = rv;
    }
}

extern "C" void kernel_launch(void* const* d_in, const int* in_sizes, int n_in,
                              void* d_out, int out_size, void* d_ws, size_t ws_size,
                              hipStream_t stream) {
    const float* rgb = (const float*)d_in[0];
    const float* ms  = (const float*)d_in[1];
    const float* Wq  = (const float*)d_in[2];
    const float* bq  = (const float*)d_in[3];
    const float* Wk  = (const float*)d_in[4];
    const float* bk  = (const float*)d_in[5];
    const float* Wv  = (const float*)d_in[6];
    const float* bv  = (const float*)d_in[7];
    const float* Wf  = (const float*)d_in[8];
    const float* bf_ = (const float*)d_in[9];
    float* outp = (float*)d_out;

    const size_t TN = (size_t)BATCH * NTOK * DIMC;      // 12.58M elems
    const size_t WN = (size_t)DIMC * DIMC;              // 147456
    u16* rgb_t = (u16*)d_ws;       // (b, n, c) bf16
    u16* ms_t  = rgb_t + TN;       // (b, n, c)
    u16* q_t   = ms_t + TN;        // (b, n, d)
    u16* k_t   = q_t + TN;         // (b, m, d)
    u16* v_cf  = k_t + TN;         // (b, d, m)
    u16* wbf   = v_cf + TN;        // Wq,Wk,Wv,Wf bf16 concat
    // total ws: 5*25.2MB + 1.2MB = 127 MB

    wcvt<<<dim3(72, 4), 256, 0, stream>>>(Wq, Wk, Wv, Wf, wbf);
    transpose_cvt<<<dim3(NTOK / 64, DIMC / 64, BATCH), 256, 0, stream>>>(rgb, rgb_t);
    transpose_cvt<<<dim3(NTOK / 64, DIMC / 64, BATCH), 256, 0, stream>>>(ms, ms_t);

    const long ts = (long)NTOK * DIMC;
    // q: rows=n (1024), cols=d (384)
    proj_mfma<<<dim3(DIMC / 64, NTOK / 64, BATCH), 256, 0, stream>>>(
        rgb_t, ts, wbf + 0 * WN, 0, q_t, ts, DIMC, bq, 0);
    // k
    proj_mfma<<<dim3(DIMC / 64, NTOK / 64, BATCH), 256, 0, stream>>>(
        ms_t, ts, wbf + 1 * WN, 0, k_t, ts, DIMC, bk, 0);
    // v: rows=d (384), cols=m (1024)
    proj_mfma<<<dim3(NTOK / 64, DIMC / 64, BATCH), 256, 0, stream>>>(
        wbf + 2 * WN, 0, ms_t, ts, v_cf, ts, NTOK, bv, 1);

    attn_mfma<<<dim3(NTOK / 64, BATCH), 256, 0, stream>>>(
        q_t, k_t, v_cf, wbf + 3 * WN, bf_, outp);
}

// Round 4
// 419.442 us; speedup vs baseline: 29.2493x; 2.0979x over previous
//
#include <hip/hip_runtime.h>

#define DIMC 384
#define NTOK 1024
#define BATCH 32
#define KT12 12

using short8 = __attribute__((ext_vector_type(8))) short;
using f32x4  = __attribute__((ext_vector_type(4))) float;
using uint4_ = __attribute__((ext_vector_type(4))) unsigned int;
typedef unsigned short u16;

#define MFMA16 __builtin_amdgcn_mfma_f32_16x16x32_bf16

__device__ __forceinline__ u16 f2bf(float f) {
    unsigned int u = __builtin_bit_cast(unsigned int, f);
    u += 0x7FFFu + ((u >> 16) & 1u);
    return (u16)(u >> 16);
}
__device__ __forceinline__ float bf2f(u16 h) {
    unsigned int u = ((unsigned int)h) << 16;
    return __builtin_bit_cast(float, u);
}

// Unified fragment-contiguous swizzle for matrix M[R][K] (K = contraction dim):
//   flat = ((r>>4)*KT + (k>>5))*512 + (((k>>3)&3)*16 + (r&15))*8 + (k&7)
// One MFMA B/A fragment (rt, kt) = 1 KB contiguous at ((rt*KT+kt)*64+lane)*8.

// ---------------------------------------------------------------------------
// transpose_sw: X (b, c, n) fp32 -> X_sw (b, unified swizzle R=n K=c) bf16.
// grid (NTOK/64, DIMC/64, BATCH), 256 threads.
// ---------------------------------------------------------------------------
__global__ __launch_bounds__(256) void transpose_sw(
    const float* __restrict__ X, u16* __restrict__ Xsw)
{
    __shared__ float tl[64 * 65];
    const int b = blockIdx.z, n0 = blockIdx.x * 64, c0 = blockIdx.y * 64;
    const int t = threadIdx.x;

#pragma unroll
    for (int p = 0; p < 4; ++p) {
        int idx = p * 256 + t;
        int c = idx >> 4, n4 = (idx & 15) * 4;
        f32x4 v = *(const f32x4*)(X + ((size_t)b * DIMC + c0 + c) * NTOK + n0 + n4);
#pragma unroll
        for (int i = 0; i < 4; ++i) tl[c * 65 + n4 + i] = v[i];
    }
    __syncthreads();
    u16* dstb = Xsw + (size_t)b * NTOK * DIMC;
#pragma unroll
    for (int p = 0; p < 2; ++p) {
        int g = p * 256 + t;  // [3:0]=n15 [5:4]=quad [6]=ktl [8:7]=rg
        int n15 = g & 15, quad = (g >> 4) & 3, ktl = (g >> 6) & 1, rg = g >> 7;
        int c8 = ktl * 32 + quad * 8;
        int nl = rg * 16 + n15;
        uint4_ pk;
#pragma unroll
        for (int i = 0; i < 4; ++i) {
            u16 lo = f2bf(tl[(c8 + 2 * i) * 65 + nl]);
            u16 hi = f2bf(tl[(c8 + 2 * i + 1) * 65 + nl]);
            pk[i] = (unsigned)lo | ((unsigned)hi << 16);
        }
        size_t dst = (((size_t)(n0 >> 4) + rg) * KT12 + (c0 >> 5) + ktl) * 512 + (size_t)(g & 63) * 8;
        *(uint4_*)(dstb + dst) = pk;
    }
}

// ---------------------------------------------------------------------------
// wcvt_sw: 4 weight matrices (384x384 fp32, row-major [d][c]) -> unified
// swizzle bf16 (R=d, K=c), concatenated. grid (72, 4), 256 threads.
// ---------------------------------------------------------------------------
__global__ __launch_bounds__(256) void wcvt_sw(
    const float* __restrict__ w0, const float* __restrict__ w1,
    const float* __restrict__ w2, const float* __restrict__ w3,
    u16* __restrict__ dst)
{
    const float* srcs[4] = {w0, w1, w2, w3};
    const float* s = srcs[blockIdx.y];
    u16* d = dst + (size_t)blockIdx.y * DIMC * DIMC;
    int e0 = (blockIdx.x * 256 + threadIdx.x) * 8;
    int dd = e0 / DIMC, c8 = e0 % DIMC;
    f32x4 a = *(const f32x4*)(s + e0);
    f32x4 b2 = *(const f32x4*)(s + e0 + 4);
    uint4_ pk;
    pk[0] = (unsigned)f2bf(a[0]) | ((unsigned)f2bf(a[1]) << 16);
    pk[1] = (unsigned)f2bf(a[2]) | ((unsigned)f2bf(a[3]) << 16);
    pk[2] = (unsigned)f2bf(b2[0]) | ((unsigned)f2bf(b2[1]) << 16);
    pk[3] = (unsigned)f2bf(b2[2]) | ((unsigned)f2bf(b2[3]) << 16);
    size_t off = ((size_t)(dd >> 4) * KT12 + (c8 >> 5)) * 512 +
                 (size_t)((((c8 >> 3) & 3) * 16 + (dd & 15)) * 8);
    *(uint4_*)(d + off) = pk;
}

// ---------------------------------------------------------------------------
// proj_sw: D[row][col] = sum_k A[row][k]*B[col][k] (+bias). A, B in unified
// swizzle (KT=12). mode 0: out bf16 unified swizzle (R=row, K=col, KT=ktd).
// mode 1: out fp32 row-major [row][col] (ld = NTOK) -- the final projection.
// 64x64 tile, 256 threads, no K-loop barriers (all frag loads coalesced 1KB).
// ---------------------------------------------------------------------------
__global__ __launch_bounds__(256) void proj_sw(
    const u16* __restrict__ Amat, long aStride,
    const u16* __restrict__ Bmat, long bStride,
    u16* __restrict__ OmatU, long oStride,
    float* __restrict__ OmatF,
    int ktd, const float* __restrict__ bias, int biasOnRow, int mode)
{
    __shared__ __align__(16) float t32[64 * 68];
    u16* t16 = (u16*)t32;

    const int bz = blockIdx.z;
    const int r0 = blockIdx.y * 64, c0 = blockIdx.x * 64;
    const int t = threadIdx.x, w = t >> 6, lane = t & 63;
    const int l15 = lane & 15, quad = lane >> 4;

    const u16* Ab = Amat + (size_t)bz * aStride;
    const u16* Bb = Bmat + (size_t)bz * bStride;

    f32x4 acc[4];
#pragma unroll
    for (int i = 0; i < 4; ++i) acc[i] = (f32x4){0.f, 0.f, 0.f, 0.f};

    const u16* aPtr = Ab + ((size_t)(r0 >> 4) + w) * (KT12 * 512) + (size_t)lane * 8;
    const u16* bPtr = Bb + (size_t)(c0 >> 4) * (KT12 * 512) + (size_t)lane * 8;
#pragma unroll
    for (int dk = 0; dk < 12; ++dk) {
        short8 af = *(const short8*)(aPtr + dk * 512);
#pragma unroll
        for (int mc = 0; mc < 4; ++mc) {
            short8 bfr = *(const short8*)(bPtr + ((size_t)mc * KT12 + dk) * 512);
            acc[mc] = MFMA16(af, bfr, acc[mc], 0, 0, 0);
        }
    }

    if (biasOnRow) {
        f32x4 bv = *(const f32x4*)(bias + r0 + w * 16 + quad * 4);
#pragma unroll
        for (int mc = 0; mc < 4; ++mc)
#pragma unroll
            for (int r = 0; r < 4; ++r) acc[mc][r] += bv[r];
    } else {
#pragma unroll
        for (int mc = 0; mc < 4; ++mc) {
            float bc = bias[c0 + mc * 16 + l15];
#pragma unroll
            for (int r = 0; r < 4; ++r) acc[mc][r] += bc;
        }
    }

    if (mode == 0) {
#pragma unroll
        for (int mc = 0; mc < 4; ++mc)
#pragma unroll
            for (int r = 0; r < 4; ++r)
                t16[(w * 16 + quad * 4 + r) * 72 + mc * 16 + l15] = f2bf(acc[mc][r]);
        __syncthreads();
        u16* Ob = OmatU + (size_t)bz * oStride;
#pragma unroll
        for (int p = 0; p < 2; ++p) {
            int g = p * 256 + t;  // [5:0]=lane' [6]=ktl [8:7]=rg
            int lan = g & 63, ktl = (g >> 6) & 1, rg = g >> 7;
            int row = rg * 16 + (lan & 15);
            int col = ktl * 32 + ((lan >> 4) & 3) * 8;
            uint4_ v = *(const uint4_*)(t16 + row * 72 + col);
            size_t dst = (((size_t)(r0 >> 4) + rg) * ktd + (c0 >> 5) + ktl) * 512 + (size_t)lan * 8;
            *(uint4_*)(Ob + dst) = v;
        }
    } else {
#pragma unroll
        for (int mc = 0; mc < 4; ++mc)
#pragma unroll
            for (int r = 0; r < 4; ++r)
                t32[(w * 16 + quad * 4 + r) * 68 + mc * 16 + l15] = acc[mc][r];
        __syncthreads();
        float* Ob = OmatF + (size_t)bz * ((size_t)DIMC * NTOK);
#pragma unroll
        for (int p = 0; p < 4; ++p) {
            int g = p * 256 + t;
            int row = g >> 4, c4 = (g & 15) * 4;
            f32x4 v = *(const f32x4*)(t32 + row * 68 + c4);
            *(f32x4*)(Ob + (size_t)(r0 + row) * NTOK + c0 + c4) = v;
        }
    }
}

// ---------------------------------------------------------------------------
// attn_mfma: flash attention, 128 q/block (8 waves x 16 q), 512 threads.
// K tiles double-buffered in LDS (register-prefetch pipeline, 1 barrier/iter);
// V frags direct coalesced global loads; P per-wave LDS; O written to ws in
// unified swizzle for the final proj. grid (BATCH, NTOK/128) -> batch-major
// so all 8 q-tiles of a batch land on one XCD.
// ---------------------------------------------------------------------------
__global__ __launch_bounds__(512, 2) void attn_mfma(
    const u16* __restrict__ qsw, const u16* __restrict__ ksw,
    const u16* __restrict__ vsw, u16* __restrict__ osw)
{
    // [0,24576): kbuf0  [24576,49152): kbuf1  [49152,58368): plds (8 x 1152)
    __shared__ __align__(16) u16 smem[58368];

    const int b  = blockIdx.x;
    const int n0 = blockIdx.y * 128;
    const int t = threadIdx.x, w = t >> 6, lane = t & 63;
    const int l15 = lane & 15, quad = lane >> 4;

    const size_t TB = (size_t)NTOK * DIMC;
    const u16* qb = qsw + (size_t)b * TB;
    const u16* kb = ksw + (size_t)b * TB;
    const u16* vb = vsw + (size_t)b * TB;

    // Q fragments resident (unified swizzle: 12 contiguous 1KB frags per wave)
    short8 qf[12];
    const u16* qp = qb + ((size_t)(n0 >> 4) + w) * (KT12 * 512) + (size_t)lane * 8;
#pragma unroll
    for (int dk = 0; dk < 12; ++dk) qf[dk] = *(const short8*)(qp + dk * 512);

    f32x4 Oa[24];
#pragma unroll
    for (int i = 0; i < 24; ++i) Oa[i] = (f32x4){0.f, 0.f, 0.f, 0.f};
    float m_run[4], l_run[4];
#pragma unroll
    for (int r = 0; r < 4; ++r) { m_run[r] = -1e30f; l_run[r] = 0.f; }

    const float sc2 = 0.05103103630798288f * 1.4426950408889634f;  // scale*log2e
    u16* pw = smem + 49152 + w * 1152;

    // prefetch K tile 0 into registers
    uint4_ kst[6];
#pragma unroll
    for (int c2 = 0; c2 < 6; ++c2)
        kst[c2] = *(const uint4_*)(kb + ((size_t)c2 * 512 + t) * 8);

    int cur = 0;
    for (int mt = 0; mt < 16; ++mt) {
        // commit staged regs -> kbuf[cur]; barrier; prefetch next tile
        u16* kc = cur ? (smem + 24576) : smem;
#pragma unroll
        for (int c2 = 0; c2 < 6; ++c2)
            *(uint4_*)(kc + ((size_t)c2 * 512 + t) * 8) = kst[c2];
        __syncthreads();
        if (mt < 15) {
            const u16* kt2 = kb + (size_t)(mt + 1) * 24576;
#pragma unroll
            for (int c2 = 0; c2 < 6; ++c2)
                kst[c2] = *(const uint4_*)(kt2 + ((size_t)c2 * 512 + t) * 8);
        }

        // ---- QK: S[16 q][64 keys] from LDS K frags ----
        f32x4 s[4];
#pragma unroll
        for (int i = 0; i < 4; ++i) s[i] = (f32x4){0.f, 0.f, 0.f, 0.f};
        const u16* kfb = kc + (size_t)lane * 8;
#pragma unroll
        for (int dk = 0; dk < 12; ++dk)
#pragma unroll
            for (int mc = 0; mc < 4; ++mc) {
                short8 kf = *(const short8*)(kfb + ((size_t)mc * KT12 + dk) * 512);
                s[mc] = MFMA16(qf[dk], kf, s[mc], 0, 0, 0);
            }
#pragma unroll
        for (int mc = 0; mc < 4; ++mc)
#pragma unroll
            for (int r = 0; r < 4; ++r) s[mc][r] *= sc2;

        // ---- online softmax (rows = quad*4+r; reduce over 16 l15 lanes) ----
        float mnew[4], alpha[4];
#pragma unroll
        for (int r = 0; r < 4; ++r) {
            float mx = fmaxf(fmaxf(s[0][r], s[1][r]), fmaxf(s[2][r], s[3][r]));
            mx = fmaxf(mx, __shfl_xor(mx, 1));
            mx = fmaxf(mx, __shfl_xor(mx, 2));
            mx = fmaxf(mx, __shfl_xor(mx, 4));
            mx = fmaxf(mx, __shfl_xor(mx, 8));
            mnew[r] = fmaxf(m_run[r], mx);
            alpha[r] = exp2f(m_run[r] - mnew[r]);
            m_run[r] = mnew[r];
        }
#pragma unroll
        for (int r = 0; r < 4; ++r) {
            float ls = 0.f;
#pragma unroll
            for (int mc = 0; mc < 4; ++mc) {
                float p = exp2f(s[mc][r] - mnew[r]);
                u16 pb = f2bf(p);
                pw[(quad * 4 + r) * 72 + mc * 16 + l15] = pb;
                ls += bf2f(pb);  // denominator from rounded P -> exact normalization
            }
            ls += __shfl_xor(ls, 1);
            ls += __shfl_xor(ls, 2);
            ls += __shfl_xor(ls, 4);
            ls += __shfl_xor(ls, 8);
            l_run[r] = l_run[r] * alpha[r] + ls;
        }
#pragma unroll
        for (int ci = 0; ci < 24; ++ci)
#pragma unroll
            for (int r = 0; r < 4; ++r) Oa[ci][r] *= alpha[r];

        // ---- PV: V frags direct from global (coalesced 1KB), P from LDS ----
        short8 pa0 = *(const short8*)(pw + l15 * 72 + quad * 8);
        short8 pa1 = *(const short8*)(pw + l15 * 72 + 32 + quad * 8);
        const u16* vp = vb + ((size_t)(mt * 2) * 64 + lane) * 8;
#pragma unroll
        for (int ci = 0; ci < 24; ++ci) {
            short8 v0 = *(const short8*)(vp + ((size_t)ci * 32) * 512);
            short8 v1 = *(const short8*)(vp + ((size_t)ci * 32 + 1) * 512);
            Oa[ci] = MFMA16(pa0, v0, Oa[ci], 0, 0, 0);
            Oa[ci] = MFMA16(pa1, v1, Oa[ci], 0, 0, 0);
        }
        cur ^= 1;
    }

    // ---- normalize + two-pass swizzled store of O (64 rows per pass) ----
    float rl[4];
#pragma unroll
    for (int r = 0; r < 4; ++r) rl[r] = 1.f / l_run[r];
    __syncthreads();  // all waves done with kbuf before aliasing as obuf
    u16* obuf = smem;  // 64 x 392
    u16* od = osw + (size_t)b * TB;
    for (int p = 0; p < 2; ++p) {
        if ((w >> 2) == p) {
            int nl = (w & 3) * 16 + quad * 4;
#pragma unroll
            for (int ci = 0; ci < 24; ++ci)
#pragma unroll
                for (int r = 0; r < 4; ++r)
                    obuf[(nl + r) * 392 + ci * 16 + l15] = f2bf(Oa[ci][r] * rl[r]);
        }
        __syncthreads();
#pragma unroll
        for (int g6 = 0; g6 < 6; ++g6) {
            int g = g6 * 512 + t;  // g = (rg*12 + kt)*64 + lane'
            int lan = g & 63, kt = (g >> 6) % 12, rg = g / (64 * 12);
            int row = rg * 16 + (lan & 15);
            int col = kt * 32 + ((lan >> 4) & 3) * 8;
            uint4_ v = *(const uint4_*)(obuf + row * 392 + col);
            size_t dst = (((size_t)(n0 >> 4) + p * 4 + rg) * KT12 + kt) * 512 + (size_t)lan * 8;
            *(uint4_*)(od + dst) = v;
        }
        __syncthreads();
    }
}

extern "C" void kernel_launch(void* const* d_in, const int* in_sizes, int n_in,
                              void* d_out, int out_size, void* d_ws, size_t ws_size,
                              hipStream_t stream) {
    const float* rgb = (const float*)d_in[0];
    const float* ms  = (const float*)d_in[1];
    const float* Wq  = (const float*)d_in[2];
    const float* bq  = (const float*)d_in[3];
    const float* Wk  = (const float*)d_in[4];
    const float* bk  = (const float*)d_in[5];
    const float* Wv  = (const float*)d_in[6];
    const float* bv  = (const float*)d_in[7];
    const float* Wf  = (const float*)d_in[8];
    const float* bf_ = (const float*)d_in[9];
    float* outp = (float*)d_out;

    const size_t TN = (size_t)BATCH * NTOK * DIMC;  // 12.58M elems
    const size_t WN = (size_t)DIMC * DIMC;          // 147456
    u16* rgb_sw = (u16*)d_ws;         // swizzle R=n K=c
    u16* ms_sw  = rgb_sw + TN;
    u16* q_sw   = ms_sw + TN;         // R=n K=d
    u16* k_sw   = q_sw + TN;          // R=m K=d
    u16* v_sw   = k_sw + TN;          // R=c K=m (KT=32)
    u16* o_sw   = v_sw + TN;          // R=n K=c
    u16* w_sw   = o_sw + TN;          // Wq,Wk,Wv,Wf swizzled concat
    // total ws: 6*25.2MB + 1.2MB = 152 MB

    const long TB = (long)NTOK * DIMC;

    wcvt_sw<<<dim3(72, 4), 256, 0, stream>>>(Wq, Wk, Wv, Wf, w_sw);
    transpose_sw<<<dim3(16, 6, BATCH), 256, 0, stream>>>(rgb, rgb_sw);
    transpose_sw<<<dim3(16, 6, BATCH), 256, 0, stream>>>(ms, ms_sw);

    // q: rows=n, cols=d  -> q_sw (KT=12), bias over cols
    proj_sw<<<dim3(6, 16, BATCH), 256, 0, stream>>>(
        rgb_sw, TB, w_sw + 0 * WN, 0, q_sw, TB, nullptr, 12, bq, 0, 0);
    // k: rows=m, cols=d  -> k_sw (KT=12)
    proj_sw<<<dim3(6, 16, BATCH), 256, 0, stream>>>(
        ms_sw, TB, w_sw + 1 * WN, 0, k_sw, TB, nullptr, 12, bk, 0, 0);
    // v: rows=d (A=Wv), cols=m (B=ms) -> v_sw (KT=32), bias over rows
    proj_sw<<<dim3(16, 6, BATCH), 256, 0, stream>>>(
        w_sw + 2 * WN, 0, ms_sw, TB, v_sw, TB, nullptr, 32, bv, 1, 0);

    attn_mfma<<<dim3(BATCH, 8), 512, 0, stream>>>(q_sw, k_sw, v_sw, o_sw);

    // final: rows=d (A=Wf), cols=n (B=o_sw) -> out fp32 (b, d, n), bias rows
    proj_sw<<<dim3(16, 6, BATCH), 256, 0, stream>>>(
        w_sw + 3 * WN, 0, o_sw, TB, nullptr, 0, outp, 12, bf_, 1, 1);
}

// Round 5
// 406.558 us; speedup vs baseline: 30.1763x; 1.0317x over previous
//
#include <hip/hip_runtime.h>

#define DIMC 384
#define NTOK 1024
#define BATCH 32
#define KT12 12

using short8 = __attribute__((ext_vector_type(8))) short;
using f32x4  = __attribute__((ext_vector_type(4))) float;
using uint4_ = __attribute__((ext_vector_type(4))) unsigned int;
typedef unsigned short u16;

#define MFMA16 __builtin_amdgcn_mfma_f32_16x16x32_bf16

// async global->LDS, 16B/lane. LDS dest = wave-uniform base + lane*16.
#define GLD_LDS16(gp, lp)                                                     \
    __builtin_amdgcn_global_load_lds(                                         \
        (const __attribute__((address_space(1))) void*)(gp),                  \
        (__attribute__((address_space(3))) void*)(lp), 16, 0, 0)

__device__ __forceinline__ u16 f2bf(float f) {
    unsigned int u = __builtin_bit_cast(unsigned int, f);
    u += 0x7FFFu + ((u >> 16) & 1u);
    return (u16)(u >> 16);
}
__device__ __forceinline__ float bf2f(u16 h) {
    unsigned int u = ((unsigned int)h) << 16;
    return __builtin_bit_cast(float, u);
}

// Unified fragment-contiguous swizzle for matrix M[R][K] (K = contraction):
//   flat = ((r>>4)*KT + (k>>5))*512 + (((k>>3)&3)*16 + (r&15))*8 + (k&7)
// One MFMA A/B fragment (rt, kt) = 1 KB contiguous at ((rt*KT+kt)*64+lane)*8.

// ---------------------------------------------------------------------------
// transpose_sw: X (b, c, n) fp32 -> X_sw (b, swizzle R=n K=c) bf16.
// grid (16, 6, BATCH), 256 threads.
// ---------------------------------------------------------------------------
__global__ __launch_bounds__(256) void transpose_sw(
    const float* __restrict__ X, u16* __restrict__ Xsw)
{
    __shared__ float tl[64 * 65];
    const int b = blockIdx.z, n0 = blockIdx.x * 64, c0 = blockIdx.y * 64;
    const int t = threadIdx.x;

#pragma unroll
    for (int p = 0; p < 4; ++p) {
        int idx = p * 256 + t;
        int c = idx >> 4, n4 = (idx & 15) * 4;
        f32x4 v = *(const f32x4*)(X + ((size_t)b * DIMC + c0 + c) * NTOK + n0 + n4);
#pragma unroll
        for (int i = 0; i < 4; ++i) tl[c * 65 + n4 + i] = v[i];
    }
    __syncthreads();
    u16* dstb = Xsw + (size_t)b * NTOK * DIMC;
#pragma unroll
    for (int p = 0; p < 2; ++p) {
        int g = p * 256 + t;  // [3:0]=n15 [5:4]=quad [6]=ktl [8:7]=rg
        int n15 = g & 15, quad = (g >> 4) & 3, ktl = (g >> 6) & 1, rg = g >> 7;
        int c8 = ktl * 32 + quad * 8;
        int nl = rg * 16 + n15;
        uint4_ pk;
#pragma unroll
        for (int i = 0; i < 4; ++i) {
            u16 lo = f2bf(tl[(c8 + 2 * i) * 65 + nl]);
            u16 hi = f2bf(tl[(c8 + 2 * i + 1) * 65 + nl]);
            pk[i] = (unsigned)lo | ((unsigned)hi << 16);
        }
        size_t dst = (((size_t)(n0 >> 4) + rg) * KT12 + (c0 >> 5) + ktl) * 512 + (size_t)(g & 63) * 8;
        *(uint4_*)(dstb + dst) = pk;
    }
}

// ---------------------------------------------------------------------------
// wcvt_sw: 4 weight matrices (384x384 fp32 [d][c]) -> swizzle bf16 (R=d, K=c),
// concatenated. Matrix 0 (Wq) pre-scaled by scale*log2e. grid (72,4), 256 thr.
// ---------------------------------------------------------------------------
__global__ __launch_bounds__(256) void wcvt_sw(
    const float* __restrict__ w0, const float* __restrict__ w1,
    const float* __restrict__ w2, const float* __restrict__ w3,
    u16* __restrict__ dst, float s0)
{
    const float* srcs[4] = {w0, w1, w2, w3};
    const float* s = srcs[blockIdx.y];
    float scl = (blockIdx.y == 0) ? s0 : 1.0f;
    u16* d = dst + (size_t)blockIdx.y * DIMC * DIMC;
    int e0 = (blockIdx.x * 256 + threadIdx.x) * 8;
    int dd = e0 / DIMC, c8 = e0 % DIMC;
    f32x4 a = *(const f32x4*)(s + e0);
    f32x4 b2 = *(const f32x4*)(s + e0 + 4);
    uint4_ pk;
    pk[0] = (unsigned)f2bf(a[0] * scl) | ((unsigned)f2bf(a[1] * scl) << 16);
    pk[1] = (unsigned)f2bf(a[2] * scl) | ((unsigned)f2bf(a[3] * scl) << 16);
    pk[2] = (unsigned)f2bf(b2[0] * scl) | ((unsigned)f2bf(b2[1] * scl) << 16);
    pk[3] = (unsigned)f2bf(b2[2] * scl) | ((unsigned)f2bf(b2[3] * scl) << 16);
    size_t off = ((size_t)(dd >> 4) * KT12 + (c8 >> 5)) * 512 +
                 (size_t)((((c8 >> 3) & 3) * 16 + (dd & 15)) * 8);
    *(uint4_*)(d + off) = pk;
}

// ---------------------------------------------------------------------------
// proj3_sw: q/k/v projections in one launch. D[row][col] = sum_k A[r][k]*B[c][k]
// + bias, out bf16 swizzled. 128x64 tile, 4 waves x 2 row-strips (B frags
// amortized over 2 MFMAs). grid (48, 3, BATCH), 256 threads.
//   s=0: A=rgb_sw B=Wq  -> q_sw (ktd=12, bias cols, x scale)
//   s=1: A=ms_sw  B=Wk  -> k_sw (ktd=12, bias cols)
//   s=2: A=Wv     B=ms_sw -> v_sw (ktd=32, bias rows)
// ---------------------------------------------------------------------------
__global__ __launch_bounds__(256) void proj3_sw(
    const u16* __restrict__ rgb_sw, const u16* __restrict__ ms_sw,
    const u16* __restrict__ w_sw,
    u16* __restrict__ q_sw, u16* __restrict__ k_sw, u16* __restrict__ v_sw,
    const float* __restrict__ bq, const float* __restrict__ bk,
    const float* __restrict__ bv, float s0)
{
    __shared__ __align__(16) u16 t16[128 * 76];
    const int s = blockIdx.y, b = blockIdx.z, tile = blockIdx.x;
    const size_t TB = (size_t)NTOK * DIMC, WN = (size_t)DIMC * DIMC;
    const u16 *A, *B; u16* O; const float* bias;
    int ktd, bRow, r0, c0; float bsc = 1.f;
    if (s == 0) {
        A = rgb_sw + b * TB; B = w_sw; O = q_sw + b * TB; bias = bq;
        ktd = 12; bRow = 0; r0 = (tile / 6) * 128; c0 = (tile % 6) * 64; bsc = s0;
    } else if (s == 1) {
        A = ms_sw + b * TB; B = w_sw + WN; O = k_sw + b * TB; bias = bk;
        ktd = 12; bRow = 0; r0 = (tile / 6) * 128; c0 = (tile % 6) * 64;
    } else {
        A = w_sw + 2 * WN; B = ms_sw + b * TB; O = v_sw + b * TB; bias = bv;
        ktd = 32; bRow = 1; r0 = (tile / 16) * 128; c0 = (tile % 16) * 64;
    }

    const int t = threadIdx.x, w = t >> 6, lane = t & 63;
    const int l15 = lane & 15, quad = lane >> 4;

    f32x4 acc[2][4];
#pragma unroll
    for (int ss = 0; ss < 2; ++ss)
#pragma unroll
        for (int mc = 0; mc < 4; ++mc) acc[ss][mc] = (f32x4){0.f, 0.f, 0.f, 0.f};

    const u16* aP = A + ((size_t)(r0 >> 4) + w * 2) * (KT12 * 512) + (size_t)lane * 8;
    const u16* bP = B + (size_t)(c0 >> 4) * (KT12 * 512) + (size_t)lane * 8;
#pragma unroll
    for (int dk = 0; dk < 12; ++dk) {
        short8 a0 = *(const short8*)(aP + dk * 512);
        short8 a1 = *(const short8*)(aP + (KT12 + dk) * 512);
#pragma unroll
        for (int mc = 0; mc < 4; ++mc) {
            short8 bf = *(const short8*)(bP + ((size_t)mc * KT12 + dk) * 512);
            acc[0][mc] = MFMA16(a0, bf, acc[0][mc], 0, 0, 0);
            acc[1][mc] = MFMA16(a1, bf, acc[1][mc], 0, 0, 0);
        }
    }

    if (bRow) {
#pragma unroll
        for (int ss = 0; ss < 2; ++ss) {
            f32x4 bv4 = *(const f32x4*)(bias + r0 + w * 32 + ss * 16 + quad * 4);
#pragma unroll
            for (int mc = 0; mc < 4; ++mc)
#pragma unroll
                for (int r = 0; r < 4; ++r) acc[ss][mc][r] += bv4[r];
        }
    } else {
#pragma unroll
        for (int mc = 0; mc < 4; ++mc) {
            float bc = bias[c0 + mc * 16 + l15] * bsc;
#pragma unroll
            for (int ss = 0; ss < 2; ++ss)
#pragma unroll
                for (int r = 0; r < 4; ++r) acc[ss][mc][r] += bc;
        }
    }

#pragma unroll
    for (int ss = 0; ss < 2; ++ss)
#pragma unroll
        for (int mc = 0; mc < 4; ++mc)
#pragma unroll
            for (int r = 0; r < 4; ++r)
                t16[(w * 32 + ss * 16 + quad * 4 + r) * 76 + mc * 16 + l15] = f2bf(acc[ss][mc][r]);
    __syncthreads();
#pragma unroll
    for (int p = 0; p < 4; ++p) {
        int g = p * 256 + t;  // [5:0]=lane' [6]=ktl [9:7]=rg
        int lan = g & 63, ktl = (g >> 6) & 1, rg = g >> 7;
        int row = rg * 16 + (lan & 15);
        int col = ktl * 32 + ((lan >> 4) & 3) * 8;
        uint4_ v = *(const uint4_*)(t16 + row * 76 + col);
        size_t dst = (((size_t)(r0 >> 4) + rg) * ktd + (c0 >> 5) + ktl) * 512 + (size_t)lan * 8;
        *(uint4_*)(O + dst) = v;
    }
}

// ---------------------------------------------------------------------------
// projf_sw: final projection. out[b][d][n] = sum_c Wf[d][c]*O[n][c] + bf.
// A=Wf (swizzle), B=o_sw (swizzle). 128x64 tile, fp32 row-major out.
// grid (48, BATCH), 256 threads.
// ---------------------------------------------------------------------------
__global__ __launch_bounds__(256) void projf_sw(
    const u16* __restrict__ wf_sw, const u16* __restrict__ osw,
    const float* __restrict__ bfp, float* __restrict__ out)
{
    __shared__ __align__(16) float t32[128 * 68];
    const int b = blockIdx.y, tile = blockIdx.x;
    const int r0 = (tile / 16) * 128, c0 = (tile % 16) * 64;
    const size_t TB = (size_t)NTOK * DIMC;

    const int t = threadIdx.x, w = t >> 6, lane = t & 63;
    const int quad = lane >> 4;

    f32x4 acc[2][4];
#pragma unroll
    for (int ss = 0; ss < 2; ++ss)
#pragma unroll
        for (int mc = 0; mc < 4; ++mc) acc[ss][mc] = (f32x4){0.f, 0.f, 0.f, 0.f};

    const u16* aP = wf_sw + ((size_t)(r0 >> 4) + w * 2) * (KT12 * 512) + (size_t)lane * 8;
    const u16* bP = osw + (size_t)b * TB + (size_t)(c0 >> 4) * (KT12 * 512) + (size_t)lane * 8;
#pragma unroll
    for (int dk = 0; dk < 12; ++dk) {
        short8 a0 = *(const short8*)(aP + dk * 512);
        short8 a1 = *(const short8*)(aP + (KT12 + dk) * 512);
#pragma unroll
        for (int mc = 0; mc < 4; ++mc) {
            short8 bf = *(const short8*)(bP + ((size_t)mc * KT12 + dk) * 512);
            acc[0][mc] = MFMA16(a0, bf, acc[0][mc], 0, 0, 0);
            acc[1][mc] = MFMA16(a1, bf, acc[1][mc], 0, 0, 0);
        }
    }
#pragma unroll
    for (int ss = 0; ss < 2; ++ss) {
        f32x4 bv4 = *(const f32x4*)(bfp + r0 + w * 32 + ss * 16 + quad * 4);
#pragma unroll
        for (int mc = 0; mc < 4; ++mc)
#pragma unroll
            for (int r = 0; r < 4; ++r) acc[ss][mc][r] += bv4[r];
    }

#pragma unroll
    for (int ss = 0; ss < 2; ++ss)
#pragma unroll
        for (int mc = 0; mc < 4; ++mc)
#pragma unroll
            for (int r = 0; r < 4; ++r)
                t32[(w * 32 + ss * 16 + quad * 4 + r) * 68 + mc * 16 + (lane & 15)] = acc[ss][mc][r];
    __syncthreads();
    float* Ob = out + (size_t)b * DIMC * NTOK;
#pragma unroll
    for (int p = 0; p < 8; ++p) {
        int g = p * 256 + t;
        int row = g >> 4, c4 = (g & 15) * 4;
        f32x4 v = *(const f32x4*)(t32 + row * 68 + c4);
        *(f32x4*)(Ob + (size_t)(r0 + row) * NTOK + c0 + c4) = v;
    }
}

// ---------------------------------------------------------------------------
// attn_mfma: flash attention, 64 q/block (4 waves x 16 q), 256 threads.
// K tile single-buffered via async global_load_lds (DMA for tile t+1 issued
// right after QK-reads barrier, lands during softmax+PV). V frags direct
// coalesced global loads. LDS 58.9 KB -> 2 blocks/CU (two independent
// barrier domains overlap phases). grid (16, BATCH).
// ---------------------------------------------------------------------------
__global__ __launch_bounds__(256, 2) void attn_mfma(
    const u16* __restrict__ qsw, const u16* __restrict__ ksw,
    const u16* __restrict__ vsw, u16* __restrict__ osw)
{
    // [0,24576): kbuf   [24576,29440): plds (4 waves x 16 x 76)
    __shared__ __align__(16) u16 smem[29440];

    const int b  = blockIdx.y;
    const int n0 = blockIdx.x * 64;
    const int t = threadIdx.x, w = t >> 6, lane = t & 63;
    const int l15 = lane & 15, quad = lane >> 4;

    const size_t TB = (size_t)NTOK * DIMC;
    const u16* qb = qsw + (size_t)b * TB;
    const u16* kb = ksw + (size_t)b * TB;
    const u16* vb = vsw + (size_t)b * TB;

    u16* kbuf = smem;
    u16* pw = smem + 24576 + w * 1216;

    // Q fragments resident (q pre-scaled by scale*log2e at projection)
    short8 qf[12];
    const u16* qp = qb + ((size_t)(n0 >> 4) + w) * (KT12 * 512) + (size_t)lane * 8;
#pragma unroll
    for (int dk = 0; dk < 12; ++dk) qf[dk] = *(const short8*)(qp + dk * 512);

    f32x4 Oa[24];
#pragma unroll
    for (int i = 0; i < 24; ++i) Oa[i] = (f32x4){0.f, 0.f, 0.f, 0.f};
    float m_run[4], l_run[4];
#pragma unroll
    for (int r = 0; r < 4; ++r) { m_run[r] = -1e30f; l_run[r] = 0.f; }

    // DMA K tile 0
#pragma unroll
    for (int c2 = 0; c2 < 12; ++c2)
        GLD_LDS16(kb + ((size_t)c2 * 256 + t) * 8, kbuf + ((size_t)c2 * 256 + w * 64) * 8);

    for (int mt = 0; mt < 16; ++mt) {
        __syncthreads();  // K tile landed (vmcnt0 drain) + prior-iter reads done

        // ---- QK: S[16 q][64 keys] from LDS K frags ----
        f32x4 s[4];
#pragma unroll
        for (int i = 0; i < 4; ++i) s[i] = (f32x4){0.f, 0.f, 0.f, 0.f};
        const u16* kfb = kbuf + (size_t)lane * 8;
#pragma unroll
        for (int dk = 0; dk < 12; ++dk)
#pragma unroll
            for (int mc = 0; mc < 4; ++mc) {
                short8 kf = *(const short8*)(kfb + ((size_t)mc * KT12 + dk) * 512);
                s[mc] = MFMA16(qf[dk], kf, s[mc], 0, 0, 0);
            }
        __syncthreads();  // all waves done reading kbuf

        // DMA next K tile; lands during softmax+PV
        if (mt < 15) {
            const u16* src = kb + (size_t)(mt + 1) * 24576;
#pragma unroll
            for (int c2 = 0; c2 < 12; ++c2)
                GLD_LDS16(src + ((size_t)c2 * 256 + t) * 8, kbuf + ((size_t)c2 * 256 + w * 64) * 8);
        }

        // ---- online softmax (log2-domain; rows = quad*4+r) ----
        float mnew[4], alpha[4];
#pragma unroll
        for (int r = 0; r < 4; ++r) {
            float mx = fmaxf(fmaxf(s[0][r], s[1][r]), fmaxf(s[2][r], s[3][r]));
            mx = fmaxf(mx, __shfl_xor(mx, 1));
            mx = fmaxf(mx, __shfl_xor(mx, 2));
            mx = fmaxf(mx, __shfl_xor(mx, 4));
            mx = fmaxf(mx, __shfl_xor(mx, 8));
            mnew[r] = fmaxf(m_run[r], mx);
            alpha[r] = exp2f(m_run[r] - mnew[r]);
            m_run[r] = mnew[r];
        }
#pragma unroll
        for (int r = 0; r < 4; ++r) {
            float ls = 0.f;
#pragma unroll
            for (int mc = 0; mc < 4; ++mc) {
                float p = exp2f(s[mc][r] - mnew[r]);
                u16 pb = f2bf(p);
                pw[(quad * 4 + r) * 76 + mc * 16 + l15] = pb;
                ls += bf2f(pb);  // denominator from rounded P -> exact normalization
            }
            ls += __shfl_xor(ls, 1);
            ls += __shfl_xor(ls, 2);
            ls += __shfl_xor(ls, 4);
            ls += __shfl_xor(ls, 8);
            l_run[r] = l_run[r] * alpha[r] + ls;
        }
#pragma unroll
        for (int ci = 0; ci < 24; ++ci)
#pragma unroll
            for (int r = 0; r < 4; ++r) Oa[ci][r] *= alpha[r];

        // ---- PV: P from per-wave LDS, V frags direct coalesced global ----
        short8 pa0 = *(const short8*)(pw + l15 * 76 + quad * 8);
        short8 pa1 = *(const short8*)(pw + l15 * 76 + 32 + quad * 8);
        const u16* vp = vb + ((size_t)(mt * 2) * 64 + lane) * 8;
#pragma unroll
        for (int ci = 0; ci < 24; ++ci) {
            short8 v0 = *(const short8*)(vp + ((size_t)ci * 32) * 512);
            short8 v1 = *(const short8*)(vp + ((size_t)ci * 32 + 1) * 512);
            Oa[ci] = MFMA16(pa0, v0, Oa[ci], 0, 0, 0);
            Oa[ci] = MFMA16(pa1, v1, Oa[ci], 0, 0, 0);
        }
    }

    // ---- normalize + swizzled store of O (aliases kbuf/plds) ----
    float rl[4];
#pragma unroll
    for (int r = 0; r < 4; ++r) rl[r] = 1.f / l_run[r];
    __syncthreads();  // all waves done with kbuf+plds
    u16* obuf = smem;  // 64 x 396
    const int nl = w * 16 + quad * 4;
#pragma unroll
    for (int ci = 0; ci < 24; ++ci)
#pragma unroll
        for (int r = 0; r < 4; ++r)
            obuf[(nl + r) * 396 + ci * 16 + l15] = f2bf(Oa[ci][r] * rl[r]);
    __syncthreads();
    u16* od = osw + (size_t)b * TB;
#pragma unroll
    for (int g6 = 0; g6 < 12; ++g6) {
        int g = g6 * 256 + t;  // g = (rg*12 + kt)*64 + lane'
        int lan = g & 63, kt = (g >> 6) % 12, rg = g / 768;
        int row = rg * 16 + (lan & 15);
        int col = kt * 32 + ((lan >> 4) & 3) * 8;
        uint4_ v = *(const uint4_*)(obuf + row * 396 + col);
        size_t dst = (((size_t)(n0 >> 4) + rg) * KT12 + kt) * 512 + (size_t)lan * 8;
        *(uint4_*)(od + dst) = v;
    }
}

extern "C" void kernel_launch(void* const* d_in, const int* in_sizes, int n_in,
                              void* d_out, int out_size, void* d_ws, size_t ws_size,
                              hipStream_t stream) {
    const float* rgb = (const float*)d_in[0];
    const float* ms  = (const float*)d_in[1];
    const float* Wq  = (const float*)d_in[2];
    const float* bq  = (const float*)d_in[3];
    const float* Wk  = (const float*)d_in[4];
    const float* bk  = (const float*)d_in[5];
    const float* Wv  = (const float*)d_in[6];
    const float* bv  = (const float*)d_in[7];
    const float* Wf  = (const float*)d_in[8];
    const float* bf_ = (const float*)d_in[9];
    float* outp = (float*)d_out;

    const float SC2 = 0.05103103630798288f * 1.4426950408889634f;  // scale*log2e

    const size_t TN = (size_t)BATCH * NTOK * DIMC;  // 12.58M elems
    const size_t WN = (size_t)DIMC * DIMC;          // 147456
    u16* rgb_sw = (u16*)d_ws;         // swizzle R=n K=c
    u16* ms_sw  = rgb_sw + TN;
    u16* q_sw   = ms_sw + TN;         // R=n K=d (pre-scaled)
    u16* k_sw   = q_sw + TN;          // R=m K=d
    u16* v_sw   = k_sw + TN;          // R=c K=m (KT=32)
    u16* o_sw   = v_sw + TN;          // R=n K=c
    u16* w_sw   = o_sw + TN;          // Wq,Wk,Wv,Wf swizzled concat
    // total ws: 6*25.2MB + 1.2MB = 152 MB

    wcvt_sw<<<dim3(72, 4), 256, 0, stream>>>(Wq, Wk, Wv, Wf, w_sw, SC2);
    transpose_sw<<<dim3(16, 6, BATCH), 256, 0, stream>>>(rgb, rgb_sw);
    transpose_sw<<<dim3(16, 6, BATCH), 256, 0, stream>>>(ms, ms_sw);

    proj3_sw<<<dim3(48, 3, BATCH), 256, 0, stream>>>(
        rgb_sw, ms_sw, w_sw, q_sw, k_sw, v_sw, bq, bk, bv, SC2);

    attn_mfma<<<dim3(16, BATCH), 256, 0, stream>>>(q_sw, k_sw, v_sw, o_sw);

    projf_sw<<<dim3(48, BATCH), 256, 0, stream>>>(w_sw + 3 * WN, o_sw, bf_, outp);
}